// Round 10
// baseline (84.238 us; speedup 1.0000x reference)
//
#include <hip/hip_runtime.h>
#include <hip/hip_bf16.h>

#define SDIM 192
#define S2 (SDIM*SDIM)        // 36864
#define S3 ((size_t)SDIM*S2)  // 7077888
#define NCH 5
#define RAD 4                 // window 9

// ---- KA: one d-slice, 8 output rows, full 192-w strip per block ----
#define STRH 8
#define RROW 16               // staged rows (8 + 2*4 halo)
#define RST 200               // uint stride per raw row: packed {i,j} bf16, 4+192+4 cols
#define WSTR 96               // uint (bf16x2) stride per wf row
#define NSTRIP (SDIM/STRH)    // 24

// ---- KB: D-axis add/sub sliding window, uint4 (8 bf16) per thread, 128-thr blocks ----
#define KB_THR 128
#define KB_KBC 8                            // w-positions per thread (one uint4 = 8 bf16)
#define KB_POSB (S2/(KB_THR*KB_KBC))        // 36
#define KB_DCH 8
#define KB_NDC (SDIM/KB_DCH)                // 24
#define KB_GRID (KB_POSB*KB_NDC)            // 864
#define NPART KB_GRID

__device__ __forceinline__ unsigned short f2bfu(float x) {
    __hip_bfloat16 h = __float2bfloat16(x);
    unsigned short u; __builtin_memcpy(&u, &h, 2); return u;
}
__device__ __forceinline__ unsigned packbf(float lo, float hi) {
    return (unsigned)f2bfu(lo) | ((unsigned)f2bfu(hi) << 16);
}
__device__ __forceinline__ float ulo(unsigned u) { return __uint_as_float(u << 16); }
__device__ __forceinline__ float uhi(unsigned u) { return __uint_as_float(u & 0xffff0000u); }

// ---------------- KA: W + H 9-tap (zero-padded) of the 5 product channels ----------------
__global__ __launch_bounds__(256) void ka_wh(const float* __restrict__ pred,
                                             const float* __restrict__ tgt,
                                             unsigned* __restrict__ BU) {
    const int b = blockIdx.x;              // d*NSTRIP + strip
    const int strip = b % NSTRIP;
    const int d = b / NSTRIP;
    const int h0 = strip * STRH;
    const size_t dbase = (size_t)d * S2;
    const int t = threadIdx.x;

    __shared__ unsigned IJ[RROW][RST];          // packed {i(lo), j(hi)} bf16 — 12.8 KB
    __shared__ unsigned wfU[NCH][RROW][WSTR];   // bf16x2 over w — 30.7 KB

    // zero the 4-col pads on both w-edges: cols 0..3 and 196..199
    if (t < RROW * 8) {
        const int r = t >> 3, p = t & 7;
        const int col = (p < 4) ? p : (192 + p);   // 0..3 / 196..199
        IJ[r][col] = 0u;
    }
    // stage interior rows: float4 global loads -> packed bf16{i,j} uint4 LDS writes
    const float4* tg4 = (const float4*)tgt;
    const float4* pr4 = (const float4*)pred;
#pragma unroll
    for (int it = 0; it < 3; ++it) {
        const int u = t + 256 * it;            // 0..767 == RROW*48-1, exact cover
        const int r = u / 48, q = u % 48;
        const int hh = h0 - RAD + r;
        float4 vi = make_float4(0.f, 0.f, 0.f, 0.f), vj = vi;
        if (hh >= 0 && hh < SDIM) {
            const size_t gi = (dbase + (size_t)hh * SDIM) / 4 + q;
            vi = tg4[gi]; vj = pr4[gi];
        }
        uint4 w;
        w.x = packbf(vi.x, vj.x); w.y = packbf(vi.y, vj.y);
        w.z = packbf(vi.z, vj.z); w.w = packbf(vi.w, vj.w);
        *(uint4*)&IJ[r][4 + 4 * q] = w;
    }
    __syncthreads();

    // W phase: thread-unit owns 4 output cols; reads 3 aligned uint4 (12 packed cols).
    // 768 units = RROW rows x 48 col-units, exactly 3 per thread.
#pragma unroll
    for (int it = 0; it < 3; ++it) {
        const int u = t + 256 * it;
        const int row = u / 48, cu = u % 48;
        const int c0 = 4 * cu;                 // output cols c0..c0+3
        // raw cols needed: c0-4 .. c0+7 -> LDS uint index (4 + c0-4) = c0, aligned
        const uint4 a = *(const uint4*)&IJ[row][c0];
        const uint4 bq = *(const uint4*)&IJ[row][c0 + 4];
        const uint4 cq = *(const uint4*)&IJ[row][c0 + 8];
        unsigned raw[12] = {a.x, a.y, a.z, a.w, bq.x, bq.y, bq.z, bq.w,
                            cq.x, cq.y, cq.z, cq.w};
        float fi[12], fj[12];
#pragma unroll
        for (int k = 0; k < 12; ++k) { fi[k] = ulo(raw[k]); fj[k] = uhi(raw[k]); }

#define W4(CH, EXPR) { \
        float pv[12]; \
        _Pragma("unroll") for (int k = 0; k < 12; ++k) pv[k] = (EXPR); \
        float s0 = 0.f; \
        _Pragma("unroll") for (int k = 0; k < 9; ++k) s0 += pv[k]; \
        const float s1 = s0 - pv[0] + pv[9]; \
        const float s2 = s1 - pv[1] + pv[10]; \
        const float s3 = s2 - pv[2] + pv[11]; \
        uint2 o; o.x = packbf(s0, s1); o.y = packbf(s2, s3); \
        *(uint2*)&wfU[CH][row][2 * cu] = o; }

        W4(0, fi[k])
        W4(1, fj[k])
        W4(2, fi[k] * fi[k])
        W4(3, fj[k] * fj[k])
        W4(4, fi[k] * fj[k])
#undef W4
    }
    __syncthreads();

    // H phase: thread owns a (channel, w-pair) column; sliding 9-sum over h, 8 outputs.
#pragma unroll
    for (int it = 0; it < 2; ++it) {
        const int col = t + 256 * it;          // 0..479 = c*96 + wp
        if (col < NCH * 96) {
            const int c = col / 96, wp = col % 96;
            float lo[RROW], hi[RROW];
#pragma unroll
            for (int r = 0; r < RROW; ++r) {
                const unsigned v = wfU[c][r][wp];
                lo[r] = ulo(v); hi[r] = uhi(v);
            }
            float slo = 0.f, shi = 0.f;
#pragma unroll
            for (int r = 0; r < 9; ++r) { slo += lo[r]; shi += hi[r]; }
            unsigned* dst = BU + (size_t)c * (S3 / 2) + (dbase + (size_t)h0 * SDIM) / 2 + wp;
            dst[0] = packbf(slo, shi);
#pragma unroll
            for (int hr = 1; hr < STRH; ++hr) {
                slo += lo[hr + 8] - lo[hr - 1];
                shi += hi[hr + 8] - hi[hr - 1];
                dst[hr * (SDIM / 2)] = packbf(slo, shi);
            }
        }
    }
}

// ---------------- KB: D-axis add/sub sliding window, uint4 loads, 128-thr blocks ----------------
#define SLICE4(s, OP) { const size_t sb = ((size_t)(s) * S2 + pos0) >> 3; \
    _Pragma("unroll") for (int c = 0; c < NCH; ++c) { \
        const uint4 v = B4[(size_t)c * (S3 >> 3) + sb]; \
        z[c][0] OP ulo(v.x); z[c][1] OP uhi(v.x); \
        z[c][2] OP ulo(v.y); z[c][3] OP uhi(v.y); \
        z[c][4] OP ulo(v.z); z[c][5] OP uhi(v.z); \
        z[c][6] OP ulo(v.w); z[c][7] OP uhi(v.w); } }

__global__ __launch_bounds__(KB_THR) void kb_d_cc(const unsigned* __restrict__ BU,
                                                  float* __restrict__ partials) {
    const int bid = blockIdx.x;
    const int dc = bid / KB_POSB;
    const int pb = bid % KB_POSB;
    const int d0 = dc * KB_DCH;
    const int pos0 = pb * (KB_THR * KB_KBC) + threadIdx.x * KB_KBC;
    const uint4* B4 = (const uint4*)BU;

    float z[NCH][KB_KBC];
#pragma unroll
    for (int c = 0; c < NCH; ++c)
#pragma unroll
        for (int i = 0; i < KB_KBC; ++i) z[c][i] = 0.f;

    // warm up: window for output d0 (slices d0-4..d0+4, zero-padded)
#pragma unroll
    for (int dd = -RAD; dd <= RAD; ++dd) {
        const int s = d0 + dd;
        if (s >= 0 && s < SDIM) SLICE4(s, +=)
    }

    const float inv = 1.0f / 729.0f;
    const float eps = 1.1920929e-07f;      // np.finfo(float32).eps
    float acc = 0.f;

#pragma unroll
    for (int k = 0; k < KB_DCH; ++k) {
        const int d = d0 + k;
#pragma unroll
        for (int i = 0; i < KB_KBC; ++i) {
            const float mu1 = z[0][i] * inv;
            const float mu2 = z[1][i] * inv;
            const float sg1 = z[2][i] * inv - mu1 * mu1;
            const float sg2 = z[3][i] * inv - mu2 * mu2;
            const float s12 = z[4][i] * inv - mu1 * mu2;
            acc += (s12 * s12) * __builtin_amdgcn_rcpf(sg1 * sg2 + eps);
        }
        const int da = d + RAD + 1;
        const int ds = d - RAD;
        if (da < SDIM) SLICE4(da, +=)
        if (ds >= 0)   SLICE4(ds, -=)
    }

    __shared__ float red[KB_THR];
    red[threadIdx.x] = acc;
    __syncthreads();
#pragma unroll
    for (int o = KB_THR / 2; o > 0; o >>= 1) {
        if (threadIdx.x < o) red[threadIdx.x] += red[threadIdx.x + o];
        __syncthreads();
    }
    if (threadIdx.x == 0) partials[bid] = red[0];
}

// ---------------- K4: final deterministic reduction ----------------
__global__ __launch_bounds__(256) void k4_finalize(const float* __restrict__ partials,
                                                   float* __restrict__ out) {
    __shared__ float sm[256];
    float s = 0.f;
    for (int i = threadIdx.x; i < NPART; i += 256) s += partials[i];
    sm[threadIdx.x] = s;
    __syncthreads();
#pragma unroll
    for (int o = 128; o > 0; o >>= 1) {
        if (threadIdx.x < o) sm[threadIdx.x] += sm[threadIdx.x + o];
        __syncthreads();
    }
    if (threadIdx.x == 0) out[0] = 1.0f - sm[0] / (float)((size_t)SDIM * S2);
}

extern "C" void kernel_launch(void* const* d_in, const int* in_sizes, int n_in,
                              void* d_out, int out_size, void* d_ws, size_t ws_size,
                              hipStream_t stream) {
    const float* pred = (const float*)d_in[0];
    const float* tgt  = (const float*)d_in[1];
    float* out = (float*)d_out;

    const size_t b_bytes = (size_t)NCH * S3 * sizeof(__hip_bfloat16);   // ~70.8 MB
    const size_t b_pad = (b_bytes + 255) & ~(size_t)255;

    unsigned* BU = (unsigned*)d_ws;
    float* partials = (float*)((char*)d_ws + b_pad);

    ka_wh<<<SDIM * NSTRIP, 256, 0, stream>>>(pred, tgt, BU);
    kb_d_cc<<<KB_GRID, KB_THR, 0, stream>>>(BU, partials);
    k4_finalize<<<1, 256, 0, stream>>>(partials, out);
}

// Round 11
// 72.725 us; speedup vs baseline: 1.1583x; 1.1583x over previous
//
#include <hip/hip_runtime.h>
#include <hip/hip_bf16.h>

#define SDIM 192
#define S2 (SDIM*SDIM)        // 36864
#define S3 ((size_t)SDIM*S2)  // 7077888
#define NCH 5
#define RAD 4                 // window 9

// ---- KA: one d-slice, 8 output rows, full 192-w strip per block ----
#define STRH 8
#define RROW 16               // staged rows (8 + 2*4 halo)
// IJ raw storage: 50 quads (200 cols) skewed by SQ(Q)=Q+(Q>>3) -> 56 quads = 224 uints
#define RQU 224
#define WSTR 96               // uint (bf16x2) stride per wf row
#define NSTRIP (SDIM/STRH)    // 24
#define SQQ(Q) ((Q) + ((Q) >> 3))

// ---- KB: D-axis add/sub sliding window, uint2 (4 bf16) per thread, 128-thr blocks ----
#define KB_THR 128
#define KB_KBC 4                            // w-positions per thread (one uint2 = 4 bf16)
#define KB_POSB (S2/(KB_THR*KB_KBC))        // 72
#define KB_DCH 8
#define KB_NDC (SDIM/KB_DCH)                // 24
#define KB_GRID (KB_POSB*KB_NDC)            // 1728
#define NPART KB_GRID

__device__ __forceinline__ unsigned short f2bfu(float x) {
    __hip_bfloat16 h = __float2bfloat16(x);
    unsigned short u; __builtin_memcpy(&u, &h, 2); return u;
}
__device__ __forceinline__ unsigned packbf(float lo, float hi) {
    return (unsigned)f2bfu(lo) | ((unsigned)f2bfu(hi) << 16);
}
__device__ __forceinline__ float ulo(unsigned u) { return __uint_as_float(u << 16); }
__device__ __forceinline__ float uhi(unsigned u) { return __uint_as_float(u & 0xffff0000u); }

// ---------------- KA: W + H 9-tap (zero-padded) of the 5 product channels ----------------
__global__ __launch_bounds__(256) void ka_wh(const float* __restrict__ pred,
                                             const float* __restrict__ tgt,
                                             unsigned* __restrict__ BU) {
    const int b = blockIdx.x;              // d*NSTRIP + strip
    const int strip = b % NSTRIP;
    const int d = b / NSTRIP;
    const int h0 = strip * STRH;
    const size_t dbase = (size_t)d * S2;
    const int t = threadIdx.x;

    __shared__ unsigned IJ[RROW][RQU];          // packed {i(lo), j(hi)} bf16, skewed quads — 14.3 KB
    __shared__ unsigned wfU[NCH][RROW][WSTR];   // bf16x2 over w — 30.7 KB

    // zero pad quads: Q=0 (cols 0..3) at uint 0..3, Q=49 (cols 196..199) at uint 220..223
    if (t < RROW * 8) {
        const int r = t >> 3, p = t & 7;
        const int col = (p < 4) ? p : (216 + p);   // 0..3 / 220..223
        IJ[r][col] = 0u;
    }
    // stage interior rows: float4 global loads -> packed bf16{i,j} uint4 to skewed quad q+1
    const float4* tg4 = (const float4*)tgt;
    const float4* pr4 = (const float4*)pred;
#pragma unroll
    for (int it = 0; it < 3; ++it) {
        const int u = t + 256 * it;            // 0..767 == RROW*48-1, exact cover
        const int r = u / 48, q = u % 48;
        const int hh = h0 - RAD + r;
        float4 vi = make_float4(0.f, 0.f, 0.f, 0.f), vj = vi;
        if (hh >= 0 && hh < SDIM) {
            const size_t gi = (dbase + (size_t)hh * SDIM) / 4 + q;
            vi = tg4[gi]; vj = pr4[gi];
        }
        uint4 w;
        w.x = packbf(vi.x, vj.x); w.y = packbf(vi.y, vj.y);
        w.z = packbf(vi.z, vj.z); w.w = packbf(vi.w, vj.w);
        *(uint4*)&IJ[r][4 * SQQ(q + 1)] = w;
    }
    __syncthreads();

    // W phase: thread-unit owns 4 output cols; reads skewed quads cu, cu+1, cu+2
    // (3 independent ds_read_b128; skew makes cu/cu+8/cu+16/cu+24 bank-distinct).
#pragma unroll
    for (int it = 0; it < 3; ++it) {
        const int u = t + 256 * it;
        const int row = u / 48, cu = u % 48;
        const int c0 = 4 * cu;                 // output cols c0..c0+3
        const uint4 a  = *(const uint4*)&IJ[row][4 * SQQ(cu)];
        const uint4 bq = *(const uint4*)&IJ[row][4 * SQQ(cu + 1)];
        const uint4 cq = *(const uint4*)&IJ[row][4 * SQQ(cu + 2)];
        unsigned raw[12] = {a.x, a.y, a.z, a.w, bq.x, bq.y, bq.z, bq.w,
                            cq.x, cq.y, cq.z, cq.w};
        float fi[12], fj[12];
#pragma unroll
        for (int k = 0; k < 12; ++k) { fi[k] = ulo(raw[k]); fj[k] = uhi(raw[k]); }

#define W4(CH, EXPR) { \
        float pv[12]; \
        _Pragma("unroll") for (int k = 0; k < 12; ++k) pv[k] = (EXPR); \
        float s0 = 0.f; \
        _Pragma("unroll") for (int k = 0; k < 9; ++k) s0 += pv[k]; \
        const float s1 = s0 - pv[0] + pv[9]; \
        const float s2 = s1 - pv[1] + pv[10]; \
        const float s3 = s2 - pv[2] + pv[11]; \
        uint2 o; o.x = packbf(s0, s1); o.y = packbf(s2, s3); \
        *(uint2*)&wfU[CH][row][2 * cu] = o; }

        W4(0, fi[k])
        W4(1, fj[k])
        W4(2, fi[k] * fi[k])
        W4(3, fj[k] * fj[k])
        W4(4, fi[k] * fj[k])
#undef W4
    }
    __syncthreads();

    // H phase: thread owns a (channel, w-pair) column; sliding 9-sum over h, 8 outputs.
#pragma unroll
    for (int it = 0; it < 2; ++it) {
        const int col = t + 256 * it;          // 0..479 = c*96 + wp
        if (col < NCH * 96) {
            const int c = col / 96, wp = col % 96;
            float lo[RROW], hi[RROW];
#pragma unroll
            for (int r = 0; r < RROW; ++r) {
                const unsigned v = wfU[c][r][wp];
                lo[r] = ulo(v); hi[r] = uhi(v);
            }
            float slo = 0.f, shi = 0.f;
#pragma unroll
            for (int r = 0; r < 9; ++r) { slo += lo[r]; shi += hi[r]; }
            unsigned* dst = BU + (size_t)c * (S3 / 2) + (dbase + (size_t)h0 * SDIM) / 2 + wp;
            dst[0] = packbf(slo, shi);
#pragma unroll
            for (int hr = 1; hr < STRH; ++hr) {
                slo += lo[hr + 8] - lo[hr - 1];
                shi += hi[hr + 8] - hi[hr - 1];
                dst[hr * (SDIM / 2)] = packbf(slo, shi);
            }
        }
    }
}

// ---------------- KB: D-axis add/sub sliding window with uint2 loads + cc + reduce ----------------
#define SLICE2(s, OP) { const size_t sb = ((size_t)(s) * S2 + pos0) >> 2; \
    _Pragma("unroll") for (int c = 0; c < NCH; ++c) { \
        const uint2 v = B2[(size_t)c * (S3 >> 2) + sb]; \
        z[c][0] OP ulo(v.x); z[c][1] OP uhi(v.x); \
        z[c][2] OP ulo(v.y); z[c][3] OP uhi(v.y); } }

__global__ __launch_bounds__(KB_THR) void kb_d_cc(const unsigned* __restrict__ BU,
                                                  float* __restrict__ partials) {
    const int bid = blockIdx.x;
    const int dc = bid / KB_POSB;
    const int pb = bid % KB_POSB;
    const int d0 = dc * KB_DCH;
    const int pos0 = pb * (KB_THR * KB_KBC) + threadIdx.x * KB_KBC;
    const uint2* B2 = (const uint2*)BU;

    float z[NCH][KB_KBC];
#pragma unroll
    for (int c = 0; c < NCH; ++c)
#pragma unroll
        for (int i = 0; i < KB_KBC; ++i) z[c][i] = 0.f;

    // warm up: window for output d0 (slices d0-4..d0+4, zero-padded)
#pragma unroll
    for (int dd = -RAD; dd <= RAD; ++dd) {
        const int s = d0 + dd;
        if (s >= 0 && s < SDIM) SLICE2(s, +=)
    }

    const float inv = 1.0f / 729.0f;
    const float eps = 1.1920929e-07f;      // np.finfo(float32).eps
    float acc = 0.f;

#pragma unroll
    for (int k = 0; k < KB_DCH; ++k) {
        const int d = d0 + k;
#pragma unroll
        for (int i = 0; i < KB_KBC; ++i) {
            const float mu1 = z[0][i] * inv;
            const float mu2 = z[1][i] * inv;
            const float sg1 = z[2][i] * inv - mu1 * mu1;
            const float sg2 = z[3][i] * inv - mu2 * mu2;
            const float s12 = z[4][i] * inv - mu1 * mu2;
            acc += (s12 * s12) * __builtin_amdgcn_rcpf(sg1 * sg2 + eps);
        }
        const int da = d + RAD + 1;
        const int ds = d - RAD;
        if (da < SDIM) SLICE2(da, +=)
        if (ds >= 0)   SLICE2(ds, -=)
    }

    __shared__ float red[KB_THR];
    red[threadIdx.x] = acc;
    __syncthreads();
#pragma unroll
    for (int o = KB_THR / 2; o > 0; o >>= 1) {
        if (threadIdx.x < o) red[threadIdx.x] += red[threadIdx.x + o];
        __syncthreads();
    }
    if (threadIdx.x == 0) partials[bid] = red[0];
}

// ---------------- K4: final deterministic reduction ----------------
__global__ __launch_bounds__(256) void k4_finalize(const float* __restrict__ partials,
                                                   float* __restrict__ out) {
    __shared__ float sm[256];
    float s = 0.f;
    for (int i = threadIdx.x; i < NPART; i += 256) s += partials[i];
    sm[threadIdx.x] = s;
    __syncthreads();
#pragma unroll
    for (int o = 128; o > 0; o >>= 1) {
        if (threadIdx.x < o) sm[threadIdx.x] += sm[threadIdx.x + o];
        __syncthreads();
    }
    if (threadIdx.x == 0) out[0] = 1.0f - sm[0] / (float)((size_t)SDIM * S2);
}

extern "C" void kernel_launch(void* const* d_in, const int* in_sizes, int n_in,
                              void* d_out, int out_size, void* d_ws, size_t ws_size,
                              hipStream_t stream) {
    const float* pred = (const float*)d_in[0];
    const float* tgt  = (const float*)d_in[1];
    float* out = (float*)d_out;

    const size_t b_bytes = (size_t)NCH * S3 * sizeof(__hip_bfloat16);   // ~70.8 MB
    const size_t b_pad = (b_bytes + 255) & ~(size_t)255;

    unsigned* BU = (unsigned*)d_ws;
    float* partials = (float*)((char*)d_ws + b_pad);

    ka_wh<<<SDIM * NSTRIP, 256, 0, stream>>>(pred, tgt, BU);
    kb_d_cc<<<KB_GRID, KB_THR, 0, stream>>>(BU, partials);
    k4_finalize<<<1, 256, 0, stream>>>(partials, out);
}